// Round 7
// baseline (307.796 us; speedup 1.0000x reference)
//
#include <hip/hip_runtime.h>
#include <math.h>

#define L 2048
#define B 8
#define D 1024
#define ND 16
#define BD (B*D)
#define CK 128              // chunk length
#define NC (L/CK)           // 16 chunks
#define SZ (B*NC*D*ND)      // per-direction state elements (2,097,152 -> 8 MB)
#define XTSZ ((size_t)B*D*L) // transposed x elements (16,777,216 -> 64 MB)

__device__ __forceinline__ float sigmoid_precise(float v) {
    return 1.0f / (1.0f + expf(-v));
}

// =====================  NEW PATH: transpose-staged  ==========================

// Phase A: per-chunk local states (both directions) + raw-x transpose to ws.
__global__ __launch_bounds__(64) void ema_summary_t_kernel(
    const float* __restrict__ x, const float* __restrict__ damp,
    const float* __restrict__ decay, const int* __restrict__ mask,
    float* __restrict__ xT, float* __restrict__ fwdS, float* __restrict__ bwdS)
{
    __shared__ float tile[CK * 16];   // raw x, [row][channel]

    const int t  = threadIdx.x;
    const int ng = t & 3;
    const int dl = t >> 2;
    const int d0 = blockIdx.x * 16;
    const int d  = d0 + dl;
    const int b  = blockIdx.y;
    const int ch = blockIdx.z;

    const float4 dp1 = reinterpret_cast<const float4*>(damp)[d * 4 + ng];
    const float4 dc1 = reinterpret_cast<const float4*>(decay)[d * 4 + ng];
    const float4 dp2 = reinterpret_cast<const float4*>(damp)[(d + D) * 4 + ng];
    const float4 dc2 = reinterpret_cast<const float4*>(decay)[(d + D) * 4 + ng];
    float q1[4], q2[4];
    q1[0] = 1.f - sigmoid_precise(dp1.x) * sigmoid_precise(dc1.x);
    q1[1] = 1.f - sigmoid_precise(dp1.y) * sigmoid_precise(dc1.y);
    q1[2] = 1.f - sigmoid_precise(dp1.z) * sigmoid_precise(dc1.z);
    q1[3] = 1.f - sigmoid_precise(dp1.w) * sigmoid_precise(dc1.w);
    q2[0] = 1.f - sigmoid_precise(dp2.x) * sigmoid_precise(dc2.x);
    q2[1] = 1.f - sigmoid_precise(dp2.y) * sigmoid_precise(dc2.y);
    q2[2] = 1.f - sigmoid_precise(dp2.z) * sigmoid_precise(dc2.z);
    q2[3] = 1.f - sigmoid_precise(dp2.w) * sigmoid_precise(dc2.w);

    const float* xp = x + (size_t)b * D + d;
    const int4*  m4 = reinterpret_cast<const int4*>(mask + (size_t)b * L + ch * CK);
    const int j0 = ch * CK;

    float E[4]  = {0.f, 0.f, 0.f, 0.f};
    float Eh[4] = {0.f, 0.f, 0.f, 0.f};
    float w2[4] = {1.f, 1.f, 1.f, 1.f};

    for (int u = 0; u < CK; u += 4) {
        const int4 mq = m4[u >> 2];
        float xv[4];
#pragma unroll
        for (int v = 0; v < 4; ++v) xv[v] = xp[(size_t)(j0 + u + v) * BD];
        if (ng == 0) {
#pragma unroll
            for (int v = 0; v < 4; ++v) tile[(u + v) * 16 + dl] = xv[v];
        }
        const float mf[4] = {(float)mq.x, (float)mq.y, (float)mq.z, (float)mq.w};
#pragma unroll
        for (int v = 0; v < 4; ++v) {
            const float xm = xv[v] * mf[v];
#pragma unroll
            for (int k = 0; k < 4; ++k) {
                E[k]  = fmaf(q1[k], E[k], xm);
                Eh[k] = fmaf(w2[k], xm, Eh[k]);
                w2[k] *= q2[k];
            }
        }
    }
    const int si = ((b * NC + ch) * D + d) * 4 + ng;
    reinterpret_cast<float4*>(fwdS)[si] = make_float4(E[0], E[1], E[2], E[3]);
    reinterpret_cast<float4*>(bwdS)[si] = make_float4(Eh[0], Eh[1], Eh[2], Eh[3]);

    __syncthreads();
    // epilogue: write raw-x transposed; each lane fills one 128-B line
    const int c    = t >> 2;
    const int part = t & 3;
    float* dst = xT + (size_t)(b * D + d0 + c) * L + j0 + part * 32;
#pragma unroll
    for (int r8 = 0; r8 < 8; ++r8) {
        const int r = part * 32 + r8 * 4;
        reinterpret_cast<float4*>(dst)[r8] =
            make_float4(tile[(r + 0) * 16 + c], tile[(r + 1) * 16 + c],
                        tile[(r + 2) * 16 + c], tile[(r + 3) * 16 + c]);
    }
}

// Phase B: prefix across chunks (in-place -> entry states). Unchanged.
__global__ __launch_bounds__(64) void ema_prefix_kernel(
    const float* __restrict__ damp, const float* __restrict__ decay,
    float* __restrict__ fwdS, float* __restrict__ bwdS)
{
    const int tid = blockIdx.x * 64 + threadIdx.x;   // B*D*4 total
    const int ng = tid & 3;
    const int d  = (tid >> 2) & (D - 1);
    const int b  = tid >> 12;

    float4* f4 = reinterpret_cast<float4*>(fwdS);
    float4* b4 = reinterpret_cast<float4*>(bwdS);

    {
        const float4 dp = reinterpret_cast<const float4*>(damp)[d * 4 + ng];
        const float4 dc = reinterpret_cast<const float4*>(decay)[d * 4 + ng];
        float qp[4];
        qp[0] = 1.f - sigmoid_precise(dp.x) * sigmoid_precise(dc.x);
        qp[1] = 1.f - sigmoid_precise(dp.y) * sigmoid_precise(dc.y);
        qp[2] = 1.f - sigmoid_precise(dp.z) * sigmoid_precise(dc.z);
        qp[3] = 1.f - sigmoid_precise(dp.w) * sigmoid_precise(dc.w);
#pragma unroll
        for (int s = 0; s < 7; ++s) { qp[0]*=qp[0]; qp[1]*=qp[1]; qp[2]*=qp[2]; qp[3]*=qp[3]; }
        float F[4] = {0.f, 0.f, 0.f, 0.f};
        for (int i = 0; i < NC; ++i) {
            const int si = ((b * NC + i) * D + d) * 4 + ng;
            const float4 E = f4[si];
            f4[si] = make_float4(F[0], F[1], F[2], F[3]);
            F[0] = fmaf(qp[0], F[0], E.x);
            F[1] = fmaf(qp[1], F[1], E.y);
            F[2] = fmaf(qp[2], F[2], E.z);
            F[3] = fmaf(qp[3], F[3], E.w);
        }
    }
    {
        const float4 dp = reinterpret_cast<const float4*>(damp)[(d + D) * 4 + ng];
        const float4 dc = reinterpret_cast<const float4*>(decay)[(d + D) * 4 + ng];
        float qp[4];
        qp[0] = 1.f - sigmoid_precise(dp.x) * sigmoid_precise(dc.x);
        qp[1] = 1.f - sigmoid_precise(dp.y) * sigmoid_precise(dc.y);
        qp[2] = 1.f - sigmoid_precise(dp.z) * sigmoid_precise(dc.z);
        qp[3] = 1.f - sigmoid_precise(dp.w) * sigmoid_precise(dc.w);
#pragma unroll
        for (int s = 0; s < 7; ++s) { qp[0]*=qp[0]; qp[1]*=qp[1]; qp[2]*=qp[2]; qp[3]*=qp[3]; }
        float G[4] = {0.f, 0.f, 0.f, 0.f};
        for (int i = NC - 1; i >= 0; --i) {
            const int si = ((b * NC + i) * D + d) * 4 + ng;
            const float4 E = b4[si];
            b4[si] = make_float4(G[0], G[1], G[2], G[3]);
            G[0] = fmaf(qp[0], G[0], E.x);
            G[1] = fmaf(qp[1], G[1], E.y);
            G[2] = fmaf(qp[2], G[2], E.z);
            G[3] = fmaf(qp[3], G[3], E.w);
        }
    }
}

// Phase C: apply, reading transposed x (contiguous float4 per channel).
__global__ __launch_bounds__(64) void ema_apply_t_kernel(
    const float* __restrict__ xT, const float* __restrict__ damp,
    const float* __restrict__ decay, const float* __restrict__ ema,
    const float* __restrict__ proj, const float* __restrict__ rw,
    const int* __restrict__ mask,
    const float* __restrict__ fwdS, const float* __restrict__ bwdS,
    float* __restrict__ out)
{
    __shared__ float tile[CK * 16];   // resid + causal per (row, channel)

    const int t  = threadIdx.x;
    const int ng = t & 3;
    const int dl = t >> 2;
    const int d  = blockIdx.x * 16 + dl;
    const int b  = blockIdx.y;
    const int ch = blockIdx.z;

    float q1[4], c1[4], q2[4], c2[4];
    {
        const float4 dp = reinterpret_cast<const float4*>(damp)[d * 4 + ng];
        const float4 dc = reinterpret_cast<const float4*>(decay)[d * 4 + ng];
        const float4 em = reinterpret_cast<const float4*>(ema)[d * 4 + ng];
        const float4 pj = reinterpret_cast<const float4*>(proj)[d * 4 + ng];
        const float p0 = sigmoid_precise(dp.x), p1 = sigmoid_precise(dp.y),
                    p2 = sigmoid_precise(dp.z), p3 = sigmoid_precise(dp.w);
        q1[0] = 1.f - p0 * sigmoid_precise(dc.x);
        q1[1] = 1.f - p1 * sigmoid_precise(dc.y);
        q1[2] = 1.f - p2 * sigmoid_precise(dc.z);
        q1[3] = 1.f - p3 * sigmoid_precise(dc.w);
        c1[0] = p0 * em.x * pj.x * 0.25f;
        c1[1] = p1 * em.y * pj.y * 0.25f;
        c1[2] = p2 * em.z * pj.z * 0.25f;
        c1[3] = p3 * em.w * pj.w * 0.25f;
    }
    {
        const float4 dp = reinterpret_cast<const float4*>(damp)[(d + D) * 4 + ng];
        const float4 dc = reinterpret_cast<const float4*>(decay)[(d + D) * 4 + ng];
        const float4 em = reinterpret_cast<const float4*>(ema)[(d + D) * 4 + ng];
        const float4 pj = reinterpret_cast<const float4*>(proj)[(d + D) * 4 + ng];
        const float p0 = sigmoid_precise(dp.x), p1 = sigmoid_precise(dp.y),
                    p2 = sigmoid_precise(dp.z), p3 = sigmoid_precise(dp.w);
        q2[0] = 1.f - p0 * sigmoid_precise(dc.x);
        q2[1] = 1.f - p1 * sigmoid_precise(dc.y);
        q2[2] = 1.f - p2 * sigmoid_precise(dc.z);
        q2[3] = 1.f - p3 * sigmoid_precise(dc.w);
        c2[0] = p0 * em.x * pj.x * 0.25f;
        c2[1] = p1 * em.y * pj.y * 0.25f;
        c2[2] = p2 * em.z * pj.z * 0.25f;
        c2[3] = p3 * em.w * pj.w * 0.25f;
    }
    const float w = rw[d];
    const int j0 = ch * CK;
    const float4* xt4 = reinterpret_cast<const float4*>(
        xT + (size_t)(b * D + d) * L + j0);
    const int4*   m4  = reinterpret_cast<const int4*>(mask + (size_t)b * L + j0);
    float*        op  = out + (size_t)b * D + d;
    const int si = ((b * NC + ch) * D + d) * 4 + ng;

    const float4 sf = reinterpret_cast<const float4*>(fwdS)[si];
    const float4 sb = reinterpret_cast<const float4*>(bwdS)[si];
    float s[4]  = {sf.x, sf.y, sf.z, sf.w};
    float tt[4] = {sb.x, sb.y, sb.z, sb.w};

    // forward sweep: residual + causal into LDS tile (same lane writes/reads)
    for (int u = 0; u < CK; u += 4) {
        const float4 xq = xt4[u >> 2];
        const int4   mq = m4[u >> 2];
        const float xv[4] = {xq.x, xq.y, xq.z, xq.w};
        const float mf[4] = {(float)mq.x, (float)mq.y, (float)mq.z, (float)mq.w};
#pragma unroll
        for (int v = 0; v < 4; ++v) {
            const float xm = xv[v] * mf[v];
            s[0] = fmaf(q1[0], s[0], xm);
            s[1] = fmaf(q1[1], s[1], xm);
            s[2] = fmaf(q1[2], s[2], xm);
            s[3] = fmaf(q1[3], s[3], xm);
            float acc = fmaf(c1[1], s[1], c1[0] * s[0]) + fmaf(c1[3], s[3], c1[2] * s[2]);
            acc += __shfl_xor(acc, 1);
            acc += __shfl_xor(acc, 2);
            if (ng == 0) tile[(u + v) * 16 + dl] = fmaf(xv[v], w, acc);
        }
    }

    // backward sweep: anti-causal + combine + silu + store
    for (int u = CK - 4; u >= 0; u -= 4) {
        const float4 xq = xt4[u >> 2];
        const int4   mq = m4[u >> 2];
        const float xv[4] = {xq.x, xq.y, xq.z, xq.w};
        const float mf[4] = {(float)mq.x, (float)mq.y, (float)mq.z, (float)mq.w};
#pragma unroll
        for (int v = 3; v >= 0; --v) {
            const float xm = xv[v] * mf[v];
            tt[0] = fmaf(q2[0], tt[0], xm);
            tt[1] = fmaf(q2[1], tt[1], xm);
            tt[2] = fmaf(q2[2], tt[2], xm);
            tt[3] = fmaf(q2[3], tt[3], xm);
            float acc = fmaf(c2[1], tt[1], c2[0] * tt[0]) + fmaf(c2[3], tt[3], c2[2] * tt[2]);
            acc += __shfl_xor(acc, 1);
            acc += __shfl_xor(acc, 2);
            if (ng == 0) {
                const float val = tile[(u + v) * 16 + dl] + acc;
                op[(size_t)(j0 + u + v) * BD] = val / (1.0f + expf(-val));
            }
        }
    }
}

// =============  FALLBACK: validated round-6 chunked path (ws >= 16 MB) =======

__global__ __launch_bounds__(64) void ema_summary_kernel(
    const float* __restrict__ x, const float* __restrict__ damp,
    const float* __restrict__ decay, const int* __restrict__ mask,
    float* __restrict__ fwdS, float* __restrict__ bwdS)
{
    const int t  = threadIdx.x;
    const int ng = t & 3;
    const int dl = t >> 2;
    const int d  = blockIdx.x * 16 + dl;
    const int b  = blockIdx.y;
    const int ch = blockIdx.z;

    const float4 dp1 = reinterpret_cast<const float4*>(damp)[d * 4 + ng];
    const float4 dc1 = reinterpret_cast<const float4*>(decay)[d * 4 + ng];
    const float4 dp2 = reinterpret_cast<const float4*>(damp)[(d + D) * 4 + ng];
    const float4 dc2 = reinterpret_cast<const float4*>(decay)[(d + D) * 4 + ng];
    float q1[4], q2[4];
    q1[0] = 1.f - sigmoid_precise(dp1.x) * sigmoid_precise(dc1.x);
    q1[1] = 1.f - sigmoid_precise(dp1.y) * sigmoid_precise(dc1.y);
    q1[2] = 1.f - sigmoid_precise(dp1.z) * sigmoid_precise(dc1.z);
    q1[3] = 1.f - sigmoid_precise(dp1.w) * sigmoid_precise(dc1.w);
    q2[0] = 1.f - sigmoid_precise(dp2.x) * sigmoid_precise(dc2.x);
    q2[1] = 1.f - sigmoid_precise(dp2.y) * sigmoid_precise(dc2.y);
    q2[2] = 1.f - sigmoid_precise(dp2.z) * sigmoid_precise(dc2.z);
    q2[3] = 1.f - sigmoid_precise(dp2.w) * sigmoid_precise(dc2.w);

    const float* xp = x + (size_t)b * D + d;
    const int*   mp = mask + (size_t)b * L;
    const int j0 = ch * CK;

    float E[4]  = {0.f, 0.f, 0.f, 0.f};
    float Eh[4] = {0.f, 0.f, 0.f, 0.f};
    float w2[4] = {1.f, 1.f, 1.f, 1.f};

    for (int u = 0; u < CK; u += 4) {
        float xv[4], mf[4];
#pragma unroll
        for (int v = 0; v < 4; ++v) {
            const int j = j0 + u + v;
            xv[v] = xp[(size_t)j * BD];
            mf[v] = (float)mp[j];
        }
#pragma unroll
        for (int v = 0; v < 4; ++v) {
            const float xm = xv[v] * mf[v];
#pragma unroll
            for (int k = 0; k < 4; ++k) {
                E[k]  = fmaf(q1[k], E[k], xm);
                Eh[k] = fmaf(w2[k], xm, Eh[k]);
                w2[k] *= q2[k];
            }
        }
    }
    const int si = ((b * NC + ch) * D + d) * 4 + ng;
    reinterpret_cast<float4*>(fwdS)[si] = make_float4(E[0], E[1], E[2], E[3]);
    reinterpret_cast<float4*>(bwdS)[si] = make_float4(Eh[0], Eh[1], Eh[2], Eh[3]);
}

__global__ __launch_bounds__(64) void ema_apply_kernel(
    const float* __restrict__ x, const float* __restrict__ damp,
    const float* __restrict__ decay, const float* __restrict__ ema,
    const float* __restrict__ proj, const float* __restrict__ rw,
    const int* __restrict__ mask,
    const float* __restrict__ fwdS, const float* __restrict__ bwdS,
    float* __restrict__ out)
{
    __shared__ float tile[CK * 16];

    const int t  = threadIdx.x;
    const int ng = t & 3;
    const int dl = t >> 2;
    const int d  = blockIdx.x * 16 + dl;
    const int b  = blockIdx.y;
    const int ch = blockIdx.z;

    float q1[4], c1[4], q2[4], c2[4];
    {
        const float4 dp = reinterpret_cast<const float4*>(damp)[d * 4 + ng];
        const float4 dc = reinterpret_cast<const float4*>(decay)[d * 4 + ng];
        const float4 em = reinterpret_cast<const float4*>(ema)[d * 4 + ng];
        const float4 pj = reinterpret_cast<const float4*>(proj)[d * 4 + ng];
        const float p0 = sigmoid_precise(dp.x), p1 = sigmoid_precise(dp.y),
                    p2 = sigmoid_precise(dp.z), p3 = sigmoid_precise(dp.w);
        q1[0] = 1.f - p0 * sigmoid_precise(dc.x);
        q1[1] = 1.f - p1 * sigmoid_precise(dc.y);
        q1[2] = 1.f - p2 * sigmoid_precise(dc.z);
        q1[3] = 1.f - p3 * sigmoid_precise(dc.w);
        c1[0] = p0 * em.x * pj.x * 0.25f;
        c1[1] = p1 * em.y * pj.y * 0.25f;
        c1[2] = p2 * em.z * pj.z * 0.25f;
        c1[3] = p3 * em.w * pj.w * 0.25f;
    }
    {
        const float4 dp = reinterpret_cast<const float4*>(damp)[(d + D) * 4 + ng];
        const float4 dc = reinterpret_cast<const float4*>(decay)[(d + D) * 4 + ng];
        const float4 em = reinterpret_cast<const float4*>(ema)[(d + D) * 4 + ng];
        const float4 pj = reinterpret_cast<const float4*>(proj)[(d + D) * 4 + ng];
        const float p0 = sigmoid_precise(dp.x), p1 = sigmoid_precise(dp.y),
                    p2 = sigmoid_precise(dp.z), p3 = sigmoid_precise(dp.w);
        q2[0] = 1.f - p0 * sigmoid_precise(dc.x);
        q2[1] = 1.f - p1 * sigmoid_precise(dc.y);
        q2[2] = 1.f - p2 * sigmoid_precise(dc.z);
        q2[3] = 1.f - p3 * sigmoid_precise(dc.w);
        c2[0] = p0 * em.x * pj.x * 0.25f;
        c2[1] = p1 * em.y * pj.y * 0.25f;
        c2[2] = p2 * em.z * pj.z * 0.25f;
        c2[3] = p3 * em.w * pj.w * 0.25f;
    }
    const float w = rw[d];
    const float* xp = x + (size_t)b * D + d;
    float*       op = out + (size_t)b * D + d;
    const int*   mp = mask + (size_t)b * L;
    const int j0 = ch * CK;
    const int si = ((b * NC + ch) * D + d) * 4 + ng;

    const float4 sf = reinterpret_cast<const float4*>(fwdS)[si];
    const float4 sb = reinterpret_cast<const float4*>(bwdS)[si];
    float s[4] = {sf.x, sf.y, sf.z, sf.w};
    float tt[4] = {sb.x, sb.y, sb.z, sb.w};

    for (int u = 0; u < CK; u += 4) {
        float xv[4], mf[4];
#pragma unroll
        for (int v = 0; v < 4; ++v) {
            const int j = j0 + u + v;
            xv[v] = xp[(size_t)j * BD];
            mf[v] = (float)mp[j];
        }
#pragma unroll
        for (int v = 0; v < 4; ++v) {
            const float xm = xv[v] * mf[v];
            s[0] = fmaf(q1[0], s[0], xm);
            s[1] = fmaf(q1[1], s[1], xm);
            s[2] = fmaf(q1[2], s[2], xm);
            s[3] = fmaf(q1[3], s[3], xm);
            float acc = fmaf(c1[1], s[1], c1[0] * s[0]) + fmaf(c1[3], s[3], c1[2] * s[2]);
            acc += __shfl_xor(acc, 1);
            acc += __shfl_xor(acc, 2);
            if (ng == 0) tile[(u + v) * 16 + dl] = fmaf(xv[v], w, acc);
        }
    }

    for (int u = CK - 4; u >= 0; u -= 4) {
        float xv[4], mf[4];
#pragma unroll
        for (int v = 0; v < 4; ++v) {
            const int j = j0 + u + v;
            xv[v] = xp[(size_t)j * BD];
            mf[v] = (float)mp[j];
        }
#pragma unroll
        for (int v = 3; v >= 0; --v) {
            const float xm = xv[v] * mf[v];
            tt[0] = fmaf(q2[0], tt[0], xm);
            tt[1] = fmaf(q2[1], tt[1], xm);
            tt[2] = fmaf(q2[2], tt[2], xm);
            tt[3] = fmaf(q2[3], tt[3], xm);
            float acc = fmaf(c2[1], tt[1], c2[0] * tt[0]) + fmaf(c2[3], tt[3], c2[2] * tt[2]);
            acc += __shfl_xor(acc, 1);
            acc += __shfl_xor(acc, 2);
            if (ng == 0) {
                const float val = tile[(u + v) * 16 + dl] + acc;
                op[(size_t)(j0 + u + v) * BD] = val / (1.0f + expf(-val));
            }
        }
    }
}

extern "C" void kernel_launch(void* const* d_in, const int* in_sizes, int n_in,
                              void* d_out, int out_size, void* d_ws, size_t ws_size,
                              hipStream_t stream) {
    const float* x     = (const float*)d_in[0];
    const float* damp  = (const float*)d_in[1];
    const float* decay = (const float*)d_in[2];
    const float* ema   = (const float*)d_in[3];
    const float* proj  = (const float*)d_in[4];
    const float* rw    = (const float*)d_in[5];
    const int*   mask  = (const int*)d_in[6];
    float* out = (float*)d_out;

    dim3 blk(64);
    dim3 gA(D / 16, B, NC);
    const size_t need_t = (XTSZ + (size_t)2 * SZ) * sizeof(float);   // 80 MiB
    if (ws_size >= need_t) {
        float* xT   = (float*)d_ws;
        float* fwdS = xT + XTSZ;
        float* bwdS = fwdS + SZ;
        ema_summary_t_kernel<<<gA, blk, 0, stream>>>(x, damp, decay, mask, xT, fwdS, bwdS);
        ema_prefix_kernel<<<dim3(B * D * 4 / 64), blk, 0, stream>>>(damp, decay, fwdS, bwdS);
        ema_apply_t_kernel<<<gA, blk, 0, stream>>>(xT, damp, decay, ema, proj, rw, mask,
                                                   fwdS, bwdS, out);
    } else {
        float* fwdS = (float*)d_ws;
        float* bwdS = fwdS + SZ;
        ema_summary_kernel<<<gA, blk, 0, stream>>>(x, damp, decay, mask, fwdS, bwdS);
        ema_prefix_kernel<<<dim3(B * D * 4 / 64), blk, 0, stream>>>(damp, decay, fwdS, bwdS);
        ema_apply_kernel<<<gA, blk, 0, stream>>>(x, damp, decay, ema, proj, rw, mask,
                                                 fwdS, bwdS, out);
    }
}